// Round 10
// baseline (358.552 us; speedup 1.0000x reference)
//
#include <hip/hip_runtime.h>

// ---------------------------------------------------------------------------
// GCN forward, bf16-MFMA edition.
//   3x (bf16 MFMA GEMM 256x256 -> bf16 T; CSR sym-norm agg + bias + relu -> bf16)
//   collapsed layer 4: pooled = (sum_u s_u*h3[u]) @ W4 + N*b4; log_softmax.
// R1: parallel 3-phase scan. R2: bf16 MFMA GEMM + bf16 activations.
// R3: wpool two-stage. R4 (FAILED): LDS tree-reduce agg -> bank conflicts.
// R5: wave-per-node agg. R6: fusions, 15 dispatches. R7: 2 nodes/wave agg.
// R8: 128x128/256thr GEMM (3 blk/CU), 334us. R9 (FAILED): 128x256/512thr GEMM
//     (2 blk/CU, LDS-epilogue) +17us — occupancy structure beats traffic savings.
// R10: GEMM reverted to R8 shape; agg3+pool fusion kept (isolate its value).
// ---------------------------------------------------------------------------

typedef __attribute__((ext_vector_type(8))) short short8;
typedef __attribute__((ext_vector_type(4))) float float4v;

__device__ __forceinline__ unsigned short f2b(float f) {
    unsigned int u = __builtin_bit_cast(unsigned int, f);
    u += 0x7fffu + ((u >> 16) & 1u);   // round-to-nearest-even
    return (unsigned short)(u >> 16);
}
__device__ __forceinline__ float b2f(unsigned short b) {
    unsigned int u = ((unsigned int)b) << 16;
    return __builtin_bit_cast(float, u);
}

// ---------------- graph preprocessing ----------------

__global__ void zero_kernel(int* __restrict__ cnt, float* __restrict__ tsum,
                            float* __restrict__ acc, int N) {
    int i = blockIdx.x * 256 + threadIdx.x;
    if (i < N) { cnt[i] = 0; tsum[i] = 0.f; }
    if (i < 256) acc[i] = 0.f;
}

__global__ void count_kernel(const int* __restrict__ dst, int* __restrict__ cnt, int E) {
    int i = blockIdx.x * blockDim.x + threadIdx.x;
    if (i < E) atomicAdd(&cnt[dst[i]], 1);
}

__global__ void blocksum_kernel(const int* __restrict__ cnt, int* __restrict__ bsum, int N) {
    __shared__ int s[256];
    int t = threadIdx.x;
    int i = blockIdx.x * 256 + t;
    s[t] = (i < N) ? cnt[i] : 0;
    __syncthreads();
    for (int d = 128; d > 0; d >>= 1) {
        if (t < d) s[t] += s[t + d];
        __syncthreads();
    }
    if (t == 0) bsum[blockIdx.x] = s[0];
}

__global__ void bscan_kernel(int* __restrict__ bsum, int B) {
    __shared__ int s[256];
    int t = threadIdx.x;
    int v = (t < B) ? bsum[t] : 0;
    s[t] = v;
    __syncthreads();
    for (int d = 1; d < 256; d <<= 1) {
        int x = (t >= d) ? s[t - d] : 0;
        __syncthreads();
        s[t] += x;
        __syncthreads();
    }
    if (t < B) bsum[t] = s[t] - v;
}

__global__ void finalize_kernel(const int* __restrict__ cnt, const int* __restrict__ bsum,
                                int* __restrict__ offs, int* __restrict__ cursor,
                                float* __restrict__ dis, int N, int E) {
    __shared__ int s[256];
    int t = threadIdx.x;
    int i = blockIdx.x * 256 + t;
    int c = (i < N) ? cnt[i] : 0;
    s[t] = c;
    __syncthreads();
    for (int d = 1; d < 256; d <<= 1) {
        int x = (t >= d) ? s[t - d] : 0;
        __syncthreads();
        s[t] += x;
        __syncthreads();
    }
    if (i < N) {
        int ex = bsum[blockIdx.x] + s[t] - c;
        offs[i] = ex;
        cursor[i] = ex;
        dis[i] = rsqrtf((float)(c + 1));
    }
    if (blockIdx.x == 0 && t == 0) offs[N] = E;
}

__global__ void scatter_outsum_kernel(const int* __restrict__ src, const int* __restrict__ dst,
                                      const float* __restrict__ dis, int* __restrict__ cursor,
                                      int* __restrict__ csr_src, float* __restrict__ csr_nrm,
                                      float* __restrict__ tsum, int E) {
    int i = blockIdx.x * blockDim.x + threadIdx.x;
    if (i < E) {
        int s = src[i], d = dst[i];
        float dd = dis[d];
        int pos = atomicAdd(&cursor[d], 1);
        csr_src[pos] = s;
        csr_nrm[pos] = dis[s] * dd;
        atomicAdd(&tsum[s], dd);
    }
}

// ---------------- dtype conversion ----------------

__global__ void convert_wt_kernel(const float* __restrict__ W1, const float* __restrict__ W2,
                                  const float* __restrict__ W3, unsigned short* __restrict__ Wt1,
                                  unsigned short* __restrict__ Wt2, unsigned short* __restrict__ Wt3) {
    const float* W = (blockIdx.y == 0) ? W1 : (blockIdx.y == 1) ? W2 : W3;
    unsigned short* Wt = (blockIdx.y == 0) ? Wt1 : (blockIdx.y == 1) ? Wt2 : Wt3;
    int n = blockIdx.x;
    int k = threadIdx.x;
    Wt[n * 256 + k] = f2b(W[k * 256 + n]);
}

// ---------------- bf16 MFMA GEMM (R8 proven shape) ----------------
// C[M,256] = A[M,256] @ W[256,256].  A: bf16 [m][k] (AFP32=0) or fp32 [m][k]
// (AFP32=1, converted in-register during staging). Wt bf16 [n][k]. C bf16.
// Block: 256 thr (4 waves), tile 128(M) x 128(N), BK=64. Grid (ceil(M/128), 2).
// LDS row stride 72 bf16 = 144 B = 9*16B -> conflict-free b128 access.
template <int AFP32>
__global__ __launch_bounds__(256, 3) void gemm_bf16_kernel(
        const void* __restrict__ Ap, const unsigned short* __restrict__ Wt,
        unsigned short* __restrict__ C, int M) {
    __shared__ unsigned short As[128 * 72];
    __shared__ unsigned short Bs[128 * 72];
    const int tid = threadIdx.x;
    const int lane = tid & 63;
    const int wave = tid >> 6;
    const int l15 = lane & 15;
    const int quad = lane >> 4;
    const int wm = wave & 1;
    const int wn = wave >> 1;
    const int m0 = blockIdx.x * 128;
    const int n0 = blockIdx.y * 128;

    float4v acc[4][4] = {};

    const int srow = tid >> 3;
    const int skof = (tid & 7) * 8;

    for (int kk = 0; kk < 256; kk += 64) {
#pragma unroll
        for (int p = 0; p < 4; p++) {
            int row = p * 32 + srow;
            int gm = m0 + row;
            if (AFP32) {
                const float* Af = (const float*)Ap;
                float4 lo = make_float4(0.f, 0.f, 0.f, 0.f);
                float4 hi = make_float4(0.f, 0.f, 0.f, 0.f);
                if (gm < M) {
                    lo = *(const float4*)&Af[(size_t)gm * 256 + kk + skof];
                    hi = *(const float4*)&Af[(size_t)gm * 256 + kk + skof + 4];
                }
                union { unsigned short u[8]; float4 v; } pk;
                pk.u[0] = f2b(lo.x); pk.u[1] = f2b(lo.y);
                pk.u[2] = f2b(lo.z); pk.u[3] = f2b(lo.w);
                pk.u[4] = f2b(hi.x); pk.u[5] = f2b(hi.y);
                pk.u[6] = f2b(hi.z); pk.u[7] = f2b(hi.w);
                *(float4*)&As[row * 72 + skof] = pk.v;
            } else {
                const unsigned short* Ab = (const unsigned short*)Ap;
                float4 av = make_float4(0.f, 0.f, 0.f, 0.f);
                if (gm < M) av = *(const float4*)&Ab[(size_t)gm * 256 + kk + skof];
                *(float4*)&As[row * 72 + skof] = av;
            }
            float4 bv = *(const float4*)&Wt[(size_t)(n0 + row) * 256 + kk + skof];
            *(float4*)&Bs[row * 72 + skof] = bv;
        }
        __syncthreads();
#pragma unroll
        for (int ks = 0; ks < 64; ks += 32) {
            short8 af[4], bf[4];
#pragma unroll
            for (int mi = 0; mi < 4; mi++)
                af[mi] = *(const short8*)&As[(wm * 64 + mi * 16 + l15) * 72 + ks + quad * 8];
#pragma unroll
            for (int nj = 0; nj < 4; nj++)
                bf[nj] = *(const short8*)&Bs[(wn * 64 + nj * 16 + l15) * 72 + ks + quad * 8];
#pragma unroll
            for (int mi = 0; mi < 4; mi++)
#pragma unroll
                for (int nj = 0; nj < 4; nj++)
                    acc[mi][nj] = __builtin_amdgcn_mfma_f32_16x16x32_bf16(
                        af[mi], bf[nj], acc[mi][nj], 0, 0, 0);
        }
        __syncthreads();
    }

#pragma unroll
    for (int mi = 0; mi < 4; mi++) {
#pragma unroll
        for (int r = 0; r < 4; r++) {
            int row = m0 + wm * 64 + mi * 16 + quad * 4 + r;
            if (row < M) {
#pragma unroll
                for (int nj = 0; nj < 4; nj++) {
                    int col = n0 + wn * 64 + nj * 16 + l15;
                    C[(size_t)row * 256 + col] = f2b(acc[mi][nj][r]);
                }
            }
        }
    }
}

// ---------------- aggregation (bf16 in/out, fp32 accum) ----------------
// TWO nodes per wave (half-wave x ushort8 = 16B/lane row), 8 nodes/block.
// POOL=1 (layer 3): also LDS-reduce s_v-weighted fp32 rows -> partial[block].
// LDS layout idx = i*256 + hw*32 + l  -> contiguous per wave, conflict-free.
template <int RELU, int POOL>
__global__ __launch_bounds__(256) void agg_bf16_kernel(
        const unsigned short* __restrict__ T, const float* __restrict__ bias,
        const int* __restrict__ offs, const int* __restrict__ csr_src,
        const float* __restrict__ csr_nrm, const float* __restrict__ dis,
        unsigned short* __restrict__ out, int N,
        const float* __restrict__ tsum, float* __restrict__ partial) {
    int hw = threadIdx.x >> 5;                 // half-wave 0..7
    int l = threadIdx.x & 31;
    int v = blockIdx.x * 8 + hw;
    int f8 = l * 8;
    float a[8] = {};
    float wv = 0.f;
    if (v < N) {
        int beg = offs[v], end = offs[v + 1];
        float dv = dis[v];
        float w = dv * dv;
        {
            short8 hs = *(const short8*)&T[(size_t)v * 256 + f8];
#pragma unroll
            for (int i = 0; i < 8; i++) a[i] = w * b2f((unsigned short)hs[i]);
        }
        int e = beg;
        for (; e + 4 <= end; e += 4) {
            int s0 = csr_src[e],     s1 = csr_src[e + 1];
            int s2 = csr_src[e + 2], s3 = csr_src[e + 3];
            float n0 = csr_nrm[e],     n1 = csr_nrm[e + 1];
            float n2 = csr_nrm[e + 2], n3 = csr_nrm[e + 3];
            short8 h0 = *(const short8*)&T[(size_t)s0 * 256 + f8];
            short8 h1 = *(const short8*)&T[(size_t)s1 * 256 + f8];
            short8 h2 = *(const short8*)&T[(size_t)s2 * 256 + f8];
            short8 h3 = *(const short8*)&T[(size_t)s3 * 256 + f8];
#pragma unroll
            for (int i = 0; i < 8; i++)
                a[i] += n0 * b2f((unsigned short)h0[i]) + n1 * b2f((unsigned short)h1[i])
                      + n2 * b2f((unsigned short)h2[i]) + n3 * b2f((unsigned short)h3[i]);
        }
        for (; e < end; e++) {
            int s = csr_src[e];
            float nm = csr_nrm[e];
            short8 h = *(const short8*)&T[(size_t)s * 256 + f8];
#pragma unroll
            for (int i = 0; i < 8; i++) a[i] += nm * b2f((unsigned short)h[i]);
        }
        float4 bv0 = *(const float4*)&bias[f8];
        float4 bv1 = *(const float4*)&bias[f8 + 4];
        a[0] += bv0.x; a[1] += bv0.y; a[2] += bv0.z; a[3] += bv0.w;
        a[4] += bv1.x; a[5] += bv1.y; a[6] += bv1.z; a[7] += bv1.w;
        if (RELU) {
#pragma unroll
            for (int i = 0; i < 8; i++) a[i] = fmaxf(a[i], 0.f);
        }
        uint4 o;
        o.x = (unsigned int)f2b(a[0]) | ((unsigned int)f2b(a[1]) << 16);
        o.y = (unsigned int)f2b(a[2]) | ((unsigned int)f2b(a[3]) << 16);
        o.z = (unsigned int)f2b(a[4]) | ((unsigned int)f2b(a[5]) << 16);
        o.w = (unsigned int)f2b(a[6]) | ((unsigned int)f2b(a[7]) << 16);
        *(uint4*)&out[(size_t)v * 256 + f8] = o;
        if (POOL) wv = dv * (dv + tsum[v]);
    }
    if (POOL) {
        __shared__ float red[2048];
#pragma unroll
        for (int i = 0; i < 8; i++) red[i * 256 + hw * 32 + l] = wv * a[i];
        __syncthreads();
        for (int s = 4; s > 0; s >>= 1) {
            if (hw < s) {
#pragma unroll
                for (int i = 0; i < 8; i++)
                    red[i * 256 + hw * 32 + l] += red[i * 256 + (hw + s) * 32 + l];
            }
            __syncthreads();
        }
        int f = threadIdx.x;
        partial[(size_t)blockIdx.x * 256 + f] = red[(f & 7) * 256 + (f >> 3)];
    }
}

// ---------------- pooled reduce ----------------
__global__ void wpool_reduce(const float* __restrict__ partial, float* __restrict__ acc, int P) {
    int f = threadIdx.x;  // 256
    float a = 0.f;
    for (int p = blockIdx.x; p < P; p += gridDim.x)
        a += partial[(size_t)p * 256 + f];
    atomicAdd(&acc[f], a);
}

// pooled = acc @ W4 + N*b4 ; out[0:128]=pooled, out[128:256]=log_softmax(pooled)
__global__ void final_kernel(const float* __restrict__ acc, const float* __restrict__ W4,
                             const float* __restrict__ b4, float* __restrict__ out, int N) {
    __shared__ float red[128];
    int c = threadIdx.x;
    float p = (float)N * b4[c];
    for (int k = 0; k < 256; k++) p += acc[k] * W4[k * 128 + c];
    out[c] = p;
    red[c] = p;
    __syncthreads();
    for (int s = 64; s > 0; s >>= 1) {
        if (c < s) red[c] = fmaxf(red[c], red[c + s]);
        __syncthreads();
    }
    float m = red[0];
    __syncthreads();
    red[c] = expf(p - m);
    __syncthreads();
    for (int s = 64; s > 0; s >>= 1) {
        if (c < s) red[c] += red[c + s];
        __syncthreads();
    }
    float lse = m + logf(red[0]);
    out[128 + c] = p - lse;
}

extern "C" void kernel_launch(void* const* d_in, const int* in_sizes, int n_in,
                              void* d_out, int out_size, void* d_ws, size_t ws_size,
                              hipStream_t stream) {
    const float* x  = (const float*)d_in[0];
    const int*   ei = (const int*)d_in[1];
    const float* W1 = (const float*)d_in[2];
    const float* b1 = (const float*)d_in[3];
    const float* W2 = (const float*)d_in[4];
    const float* b2 = (const float*)d_in[5];
    const float* W3 = (const float*)d_in[6];
    const float* b3 = (const float*)d_in[7];
    const float* W4 = (const float*)d_in[8];
    const float* b4 = (const float*)d_in[9];

    const int N = in_sizes[0] / 256;
    const int E = in_sizes[1] / 2;
    const int* src = ei;
    const int* dst = ei + E;

    char* p = (char*)d_ws;
    auto alloc = [&](size_t bytes) {
        char* r = p;
        p += (bytes + 255) & ~(size_t)255;
        return r;
    };
    int ab = (N + 7) / 8;   // agg blocks (= partial rows)

    int*            cnt     = (int*)alloc((size_t)N * 4);
    int*            offs    = (int*)alloc((size_t)(N + 1) * 4);
    int*            cursor  = (int*)alloc((size_t)N * 4);
    float*          dis     = (float*)alloc((size_t)N * 4);
    float*          tsum    = (float*)alloc((size_t)N * 4);
    int*            bsum    = (int*)alloc(1024 * 4);
    int*            csr_src = (int*)alloc((size_t)E * 4);
    float*          csr_nrm = (float*)alloc((size_t)E * 4);
    unsigned short* Wt1     = (unsigned short*)alloc(256 * 256 * 2);
    unsigned short* Wt2     = (unsigned short*)alloc(256 * 256 * 2);
    unsigned short* Wt3     = (unsigned short*)alloc(256 * 256 * 2);
    unsigned short* T       = (unsigned short*)alloc((size_t)N * 256 * 2);
    unsigned short* Abuf    = (unsigned short*)alloc((size_t)N * 256 * 2);
    float*          partial = (float*)alloc((size_t)ab * 256 * 4);
    float*          accbuf  = (float*)alloc(256 * 4);

    // ---- graph preprocessing ----
    int eb = (E + 255) / 256;
    int nb = (N + 255) / 256;  // 196; bscan assumes nb <= 256
    zero_kernel<<<nb, 256, 0, stream>>>(cnt, tsum, accbuf, N);
    count_kernel<<<eb, 256, 0, stream>>>(dst, cnt, E);
    blocksum_kernel<<<nb, 256, 0, stream>>>(cnt, bsum, N);
    bscan_kernel<<<1, 256, 0, stream>>>(bsum, nb);
    finalize_kernel<<<nb, 256, 0, stream>>>(cnt, bsum, offs, cursor, dis, N, E);
    scatter_outsum_kernel<<<eb, 256, 0, stream>>>(src, dst, dis, cursor, csr_src,
                                                  csr_nrm, tsum, E);

    // ---- weight conversion (x converted inside GEMM1) ----
    convert_wt_kernel<<<dim3(256, 3), 256, 0, stream>>>(W1, W2, W3, Wt1, Wt2, Wt3);

    // ---- layers 1..3 ----
    dim3 ggrid((N + 127) / 128, 2);
    gemm_bf16_kernel<1><<<ggrid, 256, 0, stream>>>(x, Wt1, T, N);
    agg_bf16_kernel<1, 0><<<ab, 256, 0, stream>>>(T, b1, offs, csr_src, csr_nrm, dis,
                                                  Abuf, N, nullptr, nullptr);
    gemm_bf16_kernel<0><<<ggrid, 256, 0, stream>>>(Abuf, Wt2, T, N);
    agg_bf16_kernel<1, 0><<<ab, 256, 0, stream>>>(T, b2, offs, csr_src, csr_nrm, dis,
                                                  Abuf, N, nullptr, nullptr);
    gemm_bf16_kernel<0><<<ggrid, 256, 0, stream>>>(Abuf, Wt3, T, N);
    agg_bf16_kernel<1, 1><<<ab, 256, 0, stream>>>(T, b3, offs, csr_src, csr_nrm, dis,
                                                  Abuf, N, tsum, partial);

    // ---- collapsed layer 4 + pool + log_softmax ----
    wpool_reduce<<<64, 256, 0, stream>>>(partial, accbuf, ab);
    final_kernel<<<1, 128, 0, stream>>>(accbuf, W4, b4, (float*)d_out, N);
}

// Round 11
// 328.637 us; speedup vs baseline: 1.0910x; 1.0910x over previous
//
#include <hip/hip_runtime.h>

// ---------------------------------------------------------------------------
// GCN forward, bf16-MFMA edition.
//   3x (bf16 MFMA GEMM 256x256 -> bf16 T; CSR sym-norm agg + bias + relu -> bf16)
//   collapsed layer 4: pooled = (sum_u s_u*h3[u]) @ W4 + N*b4; log_softmax.
// R1: parallel 3-phase scan. R2: bf16 MFMA GEMM + bf16 activations.
// R3: wpool two-stage. R4 (FAILED): LDS tree-reduce agg -> bank conflicts.
// R5: wave-per-node agg. R6: fusions, 15 dispatches. R7: 2 nodes/wave agg.
// R8: 128x128/256thr GEMM, separate wpool  -> 334us (best).
// R9 (FAILED): 128x256/512thr GEMM +17us. R10 (FAILED): agg3+pool fusion +24us.
// R11: exact R8 structure; bscan merged into finalize (each block scans the
//      196-entry bsum itself). Re-anchor + reproducibility check.
// ---------------------------------------------------------------------------

typedef __attribute__((ext_vector_type(8))) short short8;
typedef __attribute__((ext_vector_type(4))) float float4v;

__device__ __forceinline__ unsigned short f2b(float f) {
    unsigned int u = __builtin_bit_cast(unsigned int, f);
    u += 0x7fffu + ((u >> 16) & 1u);   // round-to-nearest-even
    return (unsigned short)(u >> 16);
}
__device__ __forceinline__ float b2f(unsigned short b) {
    unsigned int u = ((unsigned int)b) << 16;
    return __builtin_bit_cast(float, u);
}

// ---------------- graph preprocessing ----------------

__global__ void zero_kernel(int* __restrict__ cnt, float* __restrict__ tsum,
                            float* __restrict__ acc, int N) {
    int i = blockIdx.x * 256 + threadIdx.x;
    if (i < N) { cnt[i] = 0; tsum[i] = 0.f; }
    if (i < 256) acc[i] = 0.f;
}

__global__ void count_kernel(const int* __restrict__ dst, int* __restrict__ cnt, int E) {
    int i = blockIdx.x * blockDim.x + threadIdx.x;
    if (i < E) atomicAdd(&cnt[dst[i]], 1);
}

__global__ void blocksum_kernel(const int* __restrict__ cnt, int* __restrict__ bsum, int N) {
    __shared__ int s[256];
    int t = threadIdx.x;
    int i = blockIdx.x * 256 + t;
    s[t] = (i < N) ? cnt[i] : 0;
    __syncthreads();
    for (int d = 128; d > 0; d >>= 1) {
        if (t < d) s[t] += s[t + d];
        __syncthreads();
    }
    if (t == 0) bsum[blockIdx.x] = s[0];
}

// finalize with built-in scan of bsum (raw per-block sums, nb <= 256)
__global__ void finalize_kernel(const int* __restrict__ cnt, const int* __restrict__ bsum,
                                int* __restrict__ offs, int* __restrict__ cursor,
                                float* __restrict__ dis, int N, int E, int nb) {
    __shared__ int bs[256];
    __shared__ int s[256];
    int t = threadIdx.x;
    // scan block sums (inclusive) in LDS
    bs[t] = (t < nb) ? bsum[t] : 0;
    __syncthreads();
    for (int d = 1; d < 256; d <<= 1) {
        int x = (t >= d) ? bs[t - d] : 0;
        __syncthreads();
        bs[t] += x;
        __syncthreads();
    }
    int blockoff = (blockIdx.x == 0) ? 0 : bs[blockIdx.x - 1];
    // local scan of cnt chunk
    int i = blockIdx.x * 256 + t;
    int c = (i < N) ? cnt[i] : 0;
    s[t] = c;
    __syncthreads();
    for (int d = 1; d < 256; d <<= 1) {
        int x = (t >= d) ? s[t - d] : 0;
        __syncthreads();
        s[t] += x;
        __syncthreads();
    }
    if (i < N) {
        int ex = blockoff + s[t] - c;
        offs[i] = ex;
        cursor[i] = ex;
        dis[i] = rsqrtf((float)(c + 1));
    }
    if (blockIdx.x == 0 && t == 0) offs[N] = E;
}

__global__ void scatter_outsum_kernel(const int* __restrict__ src, const int* __restrict__ dst,
                                      const float* __restrict__ dis, int* __restrict__ cursor,
                                      int* __restrict__ csr_src, float* __restrict__ csr_nrm,
                                      float* __restrict__ tsum, int E) {
    int i = blockIdx.x * blockDim.x + threadIdx.x;
    if (i < E) {
        int s = src[i], d = dst[i];
        float dd = dis[d];
        int pos = atomicAdd(&cursor[d], 1);
        csr_src[pos] = s;
        csr_nrm[pos] = dis[s] * dd;
        atomicAdd(&tsum[s], dd);
    }
}

// ---------------- dtype conversion ----------------

__global__ void convert_wt_kernel(const float* __restrict__ W1, const float* __restrict__ W2,
                                  const float* __restrict__ W3, unsigned short* __restrict__ Wt1,
                                  unsigned short* __restrict__ Wt2, unsigned short* __restrict__ Wt3) {
    const float* W = (blockIdx.y == 0) ? W1 : (blockIdx.y == 1) ? W2 : W3;
    unsigned short* Wt = (blockIdx.y == 0) ? Wt1 : (blockIdx.y == 1) ? Wt2 : Wt3;
    int n = blockIdx.x;
    int k = threadIdx.x;
    Wt[n * 256 + k] = f2b(W[k * 256 + n]);
}

// ---------------- bf16 MFMA GEMM (R8 proven shape) ----------------
// C[M,256] = A[M,256] @ W[256,256].  A: bf16 [m][k] (AFP32=0) or fp32 [m][k]
// (AFP32=1, converted in-register during staging). Wt bf16 [n][k]. C bf16.
// Block: 256 thr (4 waves), tile 128(M) x 128(N), BK=64. Grid (ceil(M/128), 2).
// LDS row stride 72 bf16 = 144 B = 9*16B -> conflict-free b128 access.
template <int AFP32>
__global__ __launch_bounds__(256, 3) void gemm_bf16_kernel(
        const void* __restrict__ Ap, const unsigned short* __restrict__ Wt,
        unsigned short* __restrict__ C, int M) {
    __shared__ unsigned short As[128 * 72];
    __shared__ unsigned short Bs[128 * 72];
    const int tid = threadIdx.x;
    const int lane = tid & 63;
    const int wave = tid >> 6;
    const int l15 = lane & 15;
    const int quad = lane >> 4;
    const int wm = wave & 1;
    const int wn = wave >> 1;
    const int m0 = blockIdx.x * 128;
    const int n0 = blockIdx.y * 128;

    float4v acc[4][4] = {};

    const int srow = tid >> 3;
    const int skof = (tid & 7) * 8;

    for (int kk = 0; kk < 256; kk += 64) {
#pragma unroll
        for (int p = 0; p < 4; p++) {
            int row = p * 32 + srow;
            int gm = m0 + row;
            if (AFP32) {
                const float* Af = (const float*)Ap;
                float4 lo = make_float4(0.f, 0.f, 0.f, 0.f);
                float4 hi = make_float4(0.f, 0.f, 0.f, 0.f);
                if (gm < M) {
                    lo = *(const float4*)&Af[(size_t)gm * 256 + kk + skof];
                    hi = *(const float4*)&Af[(size_t)gm * 256 + kk + skof + 4];
                }
                union { unsigned short u[8]; float4 v; } pk;
                pk.u[0] = f2b(lo.x); pk.u[1] = f2b(lo.y);
                pk.u[2] = f2b(lo.z); pk.u[3] = f2b(lo.w);
                pk.u[4] = f2b(hi.x); pk.u[5] = f2b(hi.y);
                pk.u[6] = f2b(hi.z); pk.u[7] = f2b(hi.w);
                *(float4*)&As[row * 72 + skof] = pk.v;
            } else {
                const unsigned short* Ab = (const unsigned short*)Ap;
                float4 av = make_float4(0.f, 0.f, 0.f, 0.f);
                if (gm < M) av = *(const float4*)&Ab[(size_t)gm * 256 + kk + skof];
                *(float4*)&As[row * 72 + skof] = av;
            }
            float4 bv = *(const float4*)&Wt[(size_t)(n0 + row) * 256 + kk + skof];
            *(float4*)&Bs[row * 72 + skof] = bv;
        }
        __syncthreads();
#pragma unroll
        for (int ks = 0; ks < 64; ks += 32) {
            short8 af[4], bf[4];
#pragma unroll
            for (int mi = 0; mi < 4; mi++)
                af[mi] = *(const short8*)&As[(wm * 64 + mi * 16 + l15) * 72 + ks + quad * 8];
#pragma unroll
            for (int nj = 0; nj < 4; nj++)
                bf[nj] = *(const short8*)&Bs[(wn * 64 + nj * 16 + l15) * 72 + ks + quad * 8];
#pragma unroll
            for (int mi = 0; mi < 4; mi++)
#pragma unroll
                for (int nj = 0; nj < 4; nj++)
                    acc[mi][nj] = __builtin_amdgcn_mfma_f32_16x16x32_bf16(
                        af[mi], bf[nj], acc[mi][nj], 0, 0, 0);
        }
        __syncthreads();
    }

#pragma unroll
    for (int mi = 0; mi < 4; mi++) {
#pragma unroll
        for (int r = 0; r < 4; r++) {
            int row = m0 + wm * 64 + mi * 16 + quad * 4 + r;
            if (row < M) {
#pragma unroll
                for (int nj = 0; nj < 4; nj++) {
                    int col = n0 + wn * 64 + nj * 16 + l15;
                    C[(size_t)row * 256 + col] = f2b(acc[mi][nj][r]);
                }
            }
        }
    }
}

// ---------------- aggregation (bf16 in/out, fp32 accum) ----------------
// TWO nodes per wave (half-wave x ushort8 = 16B/lane row), 8 nodes/block.
template <int RELU>
__global__ __launch_bounds__(256) void agg_bf16_kernel(
        const unsigned short* __restrict__ T, const float* __restrict__ bias,
        const int* __restrict__ offs, const int* __restrict__ csr_src,
        const float* __restrict__ csr_nrm, const float* __restrict__ dis,
        unsigned short* __restrict__ out, int N) {
    int hw = threadIdx.x >> 5;                 // half-wave 0..7
    int l = threadIdx.x & 31;
    int v = blockIdx.x * 8 + hw;
    if (v >= N) return;
    int f8 = l * 8;
    int beg = offs[v], end = offs[v + 1];
    float dv = dis[v];
    float w = dv * dv;
    float a[8];
    {
        short8 hs = *(const short8*)&T[(size_t)v * 256 + f8];
#pragma unroll
        for (int i = 0; i < 8; i++) a[i] = w * b2f((unsigned short)hs[i]);
    }
    int e = beg;
    for (; e + 4 <= end; e += 4) {
        int s0 = csr_src[e],     s1 = csr_src[e + 1];
        int s2 = csr_src[e + 2], s3 = csr_src[e + 3];
        float n0 = csr_nrm[e],     n1 = csr_nrm[e + 1];
        float n2 = csr_nrm[e + 2], n3 = csr_nrm[e + 3];
        short8 h0 = *(const short8*)&T[(size_t)s0 * 256 + f8];
        short8 h1 = *(const short8*)&T[(size_t)s1 * 256 + f8];
        short8 h2 = *(const short8*)&T[(size_t)s2 * 256 + f8];
        short8 h3 = *(const short8*)&T[(size_t)s3 * 256 + f8];
#pragma unroll
        for (int i = 0; i < 8; i++)
            a[i] += n0 * b2f((unsigned short)h0[i]) + n1 * b2f((unsigned short)h1[i])
                  + n2 * b2f((unsigned short)h2[i]) + n3 * b2f((unsigned short)h3[i]);
    }
    for (; e < end; e++) {
        int s = csr_src[e];
        float nm = csr_nrm[e];
        short8 h = *(const short8*)&T[(size_t)s * 256 + f8];
#pragma unroll
        for (int i = 0; i < 8; i++) a[i] += nm * b2f((unsigned short)h[i]);
    }
    float4 bv0 = *(const float4*)&bias[f8];
    float4 bv1 = *(const float4*)&bias[f8 + 4];
    a[0] += bv0.x; a[1] += bv0.y; a[2] += bv0.z; a[3] += bv0.w;
    a[4] += bv1.x; a[5] += bv1.y; a[6] += bv1.z; a[7] += bv1.w;
    if (RELU) {
#pragma unroll
        for (int i = 0; i < 8; i++) a[i] = fmaxf(a[i], 0.f);
    }
    uint4 o;
    o.x = (unsigned int)f2b(a[0]) | ((unsigned int)f2b(a[1]) << 16);
    o.y = (unsigned int)f2b(a[2]) | ((unsigned int)f2b(a[3]) << 16);
    o.z = (unsigned int)f2b(a[4]) | ((unsigned int)f2b(a[5]) << 16);
    o.w = (unsigned int)f2b(a[6]) | ((unsigned int)f2b(a[7]) << 16);
    *(uint4*)&out[(size_t)v * 256 + f8] = o;
}

// ---------------- weighted pool, two-stage (R8 proven) ----------------
__global__ __launch_bounds__(256) void wpool_partial(
        const unsigned short* __restrict__ H, const float* __restrict__ dis,
        const float* __restrict__ tsum, float* __restrict__ partial, int N) {
    int tid = threadIdx.x;
    int f8 = (tid & 31) * 8;
    int rg = tid >> 5;
    float a[8] = {};
    for (int r = blockIdx.x * 8 + rg; r < N; r += gridDim.x * 8) {
        float s = dis[r] * (dis[r] + tsum[r]);
        short8 h = *(const short8*)&H[(size_t)r * 256 + f8];
#pragma unroll
        for (int i = 0; i < 8; i++) a[i] += s * b2f((unsigned short)h[i]);
    }
    __shared__ float red[8 * 256];
#pragma unroll
    for (int i = 0; i < 8; i++) red[rg * 256 + f8 + i] = a[i];
    __syncthreads();
    for (int s = 4; s > 0; s >>= 1) {
        if (rg < s) {
#pragma unroll
            for (int i = 0; i < 8; i++)
                red[rg * 256 + f8 + i] += red[(rg + s) * 256 + f8 + i];
        }
        __syncthreads();
    }
    partial[(size_t)blockIdx.x * 256 + tid] = red[tid];
}

__global__ void wpool_reduce(const float* __restrict__ partial, float* __restrict__ acc) {
    int f = threadIdx.x;
    int p0 = blockIdx.x * 32;
    float a = 0.f;
#pragma unroll
    for (int p = 0; p < 32; p++) a += partial[(size_t)(p0 + p) * 256 + f];
    atomicAdd(&acc[f], a);
}

// pooled = acc @ W4 + N*b4 ; out[0:128]=pooled, out[128:256]=log_softmax(pooled)
__global__ void final_kernel(const float* __restrict__ acc, const float* __restrict__ W4,
                             const float* __restrict__ b4, float* __restrict__ out, int N) {
    __shared__ float red[128];
    int c = threadIdx.x;
    float p = (float)N * b4[c];
    for (int k = 0; k < 256; k++) p += acc[k] * W4[k * 128 + c];
    out[c] = p;
    red[c] = p;
    __syncthreads();
    for (int s = 64; s > 0; s >>= 1) {
        if (c < s) red[c] = fmaxf(red[c], red[c + s]);
        __syncthreads();
    }
    float m = red[0];
    __syncthreads();
    red[c] = expf(p - m);
    __syncthreads();
    for (int s = 64; s > 0; s >>= 1) {
        if (c < s) red[c] += red[c + s];
        __syncthreads();
    }
    float lse = m + logf(red[0]);
    out[128 + c] = p - lse;
}

extern "C" void kernel_launch(void* const* d_in, const int* in_sizes, int n_in,
                              void* d_out, int out_size, void* d_ws, size_t ws_size,
                              hipStream_t stream) {
    const float* x  = (const float*)d_in[0];
    const int*   ei = (const int*)d_in[1];
    const float* W1 = (const float*)d_in[2];
    const float* b1 = (const float*)d_in[3];
    const float* W2 = (const float*)d_in[4];
    const float* b2 = (const float*)d_in[5];
    const float* W3 = (const float*)d_in[6];
    const float* b3 = (const float*)d_in[7];
    const float* W4 = (const float*)d_in[8];
    const float* b4 = (const float*)d_in[9];

    const int N = in_sizes[0] / 256;
    const int E = in_sizes[1] / 2;
    const int* src = ei;
    const int* dst = ei + E;

    char* p = (char*)d_ws;
    auto alloc = [&](size_t bytes) {
        char* r = p;
        p += (bytes + 255) & ~(size_t)255;
        return r;
    };
    int*            cnt     = (int*)alloc((size_t)N * 4);
    int*            offs    = (int*)alloc((size_t)(N + 1) * 4);
    int*            cursor  = (int*)alloc((size_t)N * 4);
    float*          dis     = (float*)alloc((size_t)N * 4);
    float*          tsum    = (float*)alloc((size_t)N * 4);
    int*            bsum    = (int*)alloc(1024 * 4);
    int*            csr_src = (int*)alloc((size_t)E * 4);
    float*          csr_nrm = (float*)alloc((size_t)E * 4);
    unsigned short* Wt1     = (unsigned short*)alloc(256 * 256 * 2);
    unsigned short* Wt2     = (unsigned short*)alloc(256 * 256 * 2);
    unsigned short* Wt3     = (unsigned short*)alloc(256 * 256 * 2);
    unsigned short* T       = (unsigned short*)alloc((size_t)N * 256 * 2);
    unsigned short* Abuf    = (unsigned short*)alloc((size_t)N * 256 * 2);
    float*          partial = (float*)alloc((size_t)1024 * 256 * 4);
    float*          accbuf  = (float*)alloc(256 * 4);

    // ---- graph preprocessing ----
    int eb = (E + 255) / 256;
    int nb = (N + 255) / 256;  // 196; finalize's bsum scan assumes nb <= 256
    zero_kernel<<<nb, 256, 0, stream>>>(cnt, tsum, accbuf, N);
    count_kernel<<<eb, 256, 0, stream>>>(dst, cnt, E);
    blocksum_kernel<<<nb, 256, 0, stream>>>(cnt, bsum, N);
    finalize_kernel<<<nb, 256, 0, stream>>>(cnt, bsum, offs, cursor, dis, N, E, nb);
    scatter_outsum_kernel<<<eb, 256, 0, stream>>>(src, dst, dis, cursor, csr_src,
                                                  csr_nrm, tsum, E);

    // ---- weight conversion (x converted inside GEMM1) ----
    convert_wt_kernel<<<dim3(256, 3), 256, 0, stream>>>(W1, W2, W3, Wt1, Wt2, Wt3);

    // ---- layers 1..3 ----
    dim3 ggrid((N + 127) / 128, 2);
    int ab = (N + 7) / 8;
    gemm_bf16_kernel<1><<<ggrid, 256, 0, stream>>>(x, Wt1, T, N);
    agg_bf16_kernel<1><<<ab, 256, 0, stream>>>(T, b1, offs, csr_src, csr_nrm, dis, Abuf, N);
    gemm_bf16_kernel<0><<<ggrid, 256, 0, stream>>>(Abuf, Wt2, T, N);
    agg_bf16_kernel<1><<<ab, 256, 0, stream>>>(T, b2, offs, csr_src, csr_nrm, dis, Abuf, N);
    gemm_bf16_kernel<0><<<ggrid, 256, 0, stream>>>(Abuf, Wt3, T, N);
    agg_bf16_kernel<1><<<ab, 256, 0, stream>>>(T, b3, offs, csr_src, csr_nrm, dis, Abuf, N);

    // ---- collapsed layer 4 + pool + log_softmax ----
    wpool_partial<<<1024, 256, 0, stream>>>(Abuf, dis, tsum, partial, N);
    wpool_reduce<<<32, 256, 0, stream>>>(partial, accbuf);
    final_kernel<<<1, 128, 0, stream>>>(accbuf, W4, b4, (float*)d_out, N);
}